// Round 1
// baseline (40.482 us; speedup 1.0000x reference)
//
#include <hip/hip_runtime.h>

#define EDIM 256  // embed dim, fixed by problem

// Kernel 1: s[d] = sum_e target[e][d] / ||target[e]||
// One wave (64 lanes) per row; lane l holds float4 at d = 4l..4l+3.
__global__ void __launch_bounds__(256) target_dirsum_kernel(
    const float* __restrict__ target, float* __restrict__ s, int E) {
  const int lane = threadIdx.x & 63;
  const int gwave = (blockIdx.x * blockDim.x + threadIdx.x) >> 6;
  const int nwaves = (gridDim.x * blockDim.x) >> 6;

  float a0 = 0.f, a1 = 0.f, a2 = 0.f, a3 = 0.f;
  for (int e = gwave; e < E; e += nwaves) {
    float4 v = *reinterpret_cast<const float4*>(target + (size_t)e * EDIM + lane * 4);
    float ss = v.x * v.x + v.y * v.y + v.z * v.z + v.w * v.w;
#pragma unroll
    for (int off = 32; off >= 1; off >>= 1) ss += __shfl_xor(ss, off);
    float rn = (ss > 1e-35f) ? rsqrtf(ss) : 0.f;
    a0 += v.x * rn; a1 += v.y * rn; a2 += v.z * rn; a3 += v.w * rn;
  }
  float* sd = s + lane * 4;
  atomicAdd(sd + 0, a0);
  atomicAdd(sd + 1, a1);
  atomicAdd(sd + 2, a2);
  atomicAdd(sd + 3, a3);
}

// Kernel 2: out[n] = -(v_n . s) / ||v_n||
// One wave per row of node_emb.
__global__ void __launch_bounds__(256) dist_rowsum_kernel(
    const float* __restrict__ emb, const float* __restrict__ s,
    float* __restrict__ out, int N) {
  const int lane = threadIdx.x & 63;
  const int wib = threadIdx.x >> 6;  // wave in block (0..3)
  const int n = blockIdx.x * 4 + wib;

  // Each lane's slice of s (broadcast read; L1/L2 resident).
  float4 sf = *reinterpret_cast<const float4*>(s + lane * 4);

  if (n >= N) return;

  float4 v = *reinterpret_cast<const float4*>(emb + (size_t)n * EDIM + lane * 4);
  float dot = v.x * sf.x + v.y * sf.y + v.z * sf.z + v.w * sf.w;
  float ss  = v.x * v.x  + v.y * v.y  + v.z * v.z  + v.w * v.w;
#pragma unroll
  for (int off = 32; off >= 1; off >>= 1) {
    dot += __shfl_xor(dot, off);
    ss  += __shfl_xor(ss, off);
  }
  if (lane == 0) {
    float denom = sqrtf(ss);
    out[n] = (denom > 0.f) ? (-dot / denom) : 0.f;
  }
}

extern "C" void kernel_launch(void* const* d_in, const int* in_sizes, int n_in,
                              void* d_out, int out_size, void* d_ws, size_t ws_size,
                              hipStream_t stream) {
  // inputs: [0]=pred (unused), [1]=target [E,256], [2]=node_emb [N,256]
  const float* target = (const float*)d_in[1];
  const float* emb    = (const float*)d_in[2];
  float* out = (float*)d_out;
  float* s   = (float*)d_ws;  // 256 floats of scratch

  const int E = in_sizes[1] / EDIM;
  const int N = in_sizes[2] / EDIM;

  hipMemsetAsync(s, 0, EDIM * sizeof(float), stream);

  // Kernel 1: 32 blocks x 256 threads = 128 waves over E=2048 rows.
  target_dirsum_kernel<<<32, 256, 0, stream>>>(target, s, E);

  // Kernel 2: one wave per row, 4 waves per block.
  dist_rowsum_kernel<<<(N + 3) / 4, 256, 0, stream>>>(emb, s, out, N);
}

// Round 2
// 27.999 us; speedup vs baseline: 1.4458x; 1.4458x over previous
//
#include <hip/hip_runtime.h>

#define EDIM 256   // embed dim, fixed by problem
#define NPART 32   // partial-sum blocks for kernel A

// Kernel A: partial[b][d] = sum over this block's rows of target[e][d]/||t_e||.
// 32 blocks x 256 threads (4 waves). One wave per row slice; LDS reduce across
// the 4 waves; plain float4 store of the block partial (no atomics, no memset).
__global__ void __launch_bounds__(256) dirsum_partial_kernel(
    const float* __restrict__ target, float* __restrict__ partial, int E) {
  __shared__ float4 red[4][64];
  const int lane = threadIdx.x & 63;
  const int wib  = threadIdx.x >> 6;                 // wave in block, 0..3
  const int gwave  = blockIdx.x * 4 + wib;
  const int nwaves = gridDim.x * 4;

  float a0 = 0.f, a1 = 0.f, a2 = 0.f, a3 = 0.f;
  for (int e = gwave; e < E; e += nwaves) {
    float4 v = *reinterpret_cast<const float4*>(target + (size_t)e * EDIM + lane * 4);
    float ss = v.x * v.x + v.y * v.y + v.z * v.z + v.w * v.w;
#pragma unroll
    for (int off = 32; off >= 1; off >>= 1) ss += __shfl_xor(ss, off);
    float rn = (ss > 1e-35f) ? rsqrtf(ss) : 0.f;
    a0 += v.x * rn; a1 += v.y * rn; a2 += v.z * rn; a3 += v.w * rn;
  }
  red[wib][lane] = make_float4(a0, a1, a2, a3);
  __syncthreads();
  if (wib == 0) {
    float4 r0 = red[0][lane], r1 = red[1][lane], r2 = red[2][lane], r3 = red[3][lane];
    float4 o = make_float4(r0.x + r1.x + r2.x + r3.x,
                           r0.y + r1.y + r2.y + r3.y,
                           r0.z + r1.z + r2.z + r3.z,
                           r0.w + r1.w + r2.w + r3.w);
    *reinterpret_cast<float4*>(partial + (size_t)blockIdx.x * EDIM + lane * 4) = o;
  }
}

// Kernel B: out[n] = -(v_n . s) / ||v_n||, where s = sum of the 32 partials.
// Each thread first accumulates its lane's slice of s (broadcast, cache-hot),
// then grid-strides rows, 2 rows in flight per wave.
__global__ void __launch_bounds__(256) dist_rowsum_kernel(
    const float* __restrict__ emb, const float* __restrict__ partial,
    float* __restrict__ out, int N) {
  const int lane = threadIdx.x & 63;

  float4 sf = make_float4(0.f, 0.f, 0.f, 0.f);
#pragma unroll
  for (int b = 0; b < NPART; ++b) {
    float4 p = *reinterpret_cast<const float4*>(partial + (size_t)b * EDIM + lane * 4);
    sf.x += p.x; sf.y += p.y; sf.z += p.z; sf.w += p.w;
  }

  const int gwave  = (blockIdx.x * blockDim.x + threadIdx.x) >> 6;
  const int nwaves = (gridDim.x * blockDim.x) >> 6;

  int n = gwave;
  for (; n + nwaves < N; n += 2 * nwaves) {
    const int n2 = n + nwaves;
    float4 v0 = *reinterpret_cast<const float4*>(emb + (size_t)n  * EDIM + lane * 4);
    float4 v1 = *reinterpret_cast<const float4*>(emb + (size_t)n2 * EDIM + lane * 4);
    float dot0 = v0.x * sf.x + v0.y * sf.y + v0.z * sf.z + v0.w * sf.w;
    float ss0  = v0.x * v0.x + v0.y * v0.y + v0.z * v0.z + v0.w * v0.w;
    float dot1 = v1.x * sf.x + v1.y * sf.y + v1.z * sf.z + v1.w * sf.w;
    float ss1  = v1.x * v1.x + v1.y * v1.y + v1.z * v1.z + v1.w * v1.w;
#pragma unroll
    for (int off = 32; off >= 1; off >>= 1) {
      dot0 += __shfl_xor(dot0, off);
      ss0  += __shfl_xor(ss0, off);
      dot1 += __shfl_xor(dot1, off);
      ss1  += __shfl_xor(ss1, off);
    }
    if (lane == 0) {
      float d0 = sqrtf(ss0), d1 = sqrtf(ss1);
      out[n]  = (d0 > 0.f) ? (-dot0 / d0) : 0.f;
      out[n2] = (d1 > 0.f) ? (-dot1 / d1) : 0.f;
    }
  }
  if (n < N) {
    float4 v = *reinterpret_cast<const float4*>(emb + (size_t)n * EDIM + lane * 4);
    float dot = v.x * sf.x + v.y * sf.y + v.z * sf.z + v.w * sf.w;
    float ss  = v.x * v.x + v.y * v.y + v.z * v.z + v.w * v.w;
#pragma unroll
    for (int off = 32; off >= 1; off >>= 1) {
      dot += __shfl_xor(dot, off);
      ss  += __shfl_xor(ss, off);
    }
    if (lane == 0) {
      float d = sqrtf(ss);
      out[n] = (d > 0.f) ? (-dot / d) : 0.f;
    }
  }
}

extern "C" void kernel_launch(void* const* d_in, const int* in_sizes, int n_in,
                              void* d_out, int out_size, void* d_ws, size_t ws_size,
                              hipStream_t stream) {
  // inputs: [0]=pred (unused), [1]=target [E,256], [2]=node_emb [N,256]
  const float* target = (const float*)d_in[1];
  const float* emb    = (const float*)d_in[2];
  float* out     = (float*)d_out;
  float* partial = (float*)d_ws;   // NPART * EDIM floats, fully rewritten each call

  const int E = in_sizes[1] / EDIM;
  const int N = in_sizes[2] / EDIM;

  dirsum_partial_kernel<<<NPART, 256, 0, stream>>>(target, partial, E);
  dist_rowsum_kernel<<<1024, 256, 0, stream>>>(emb, partial, out, N);
}

// Round 3
// 25.381 us; speedup vs baseline: 1.5950x; 1.1032x over previous
//
#include <hip/hip_runtime.h>

#define EDIM 256   // embed dim, fixed by problem
#define NPART 32   // partial-sum blocks for kernel A

// Kernel A: partial[b][d] = sum over this block's rows of target[e][d]/||t_e||.
// 32 blocks x 256 threads (4 waves). Wave per row; LDS reduce across waves.
__global__ void __launch_bounds__(256) dirsum_partial_kernel(
    const float* __restrict__ target, float* __restrict__ partial, int E) {
  __shared__ float4 red[4][64];
  const int lane = threadIdx.x & 63;
  const int wib  = threadIdx.x >> 6;
  const int gwave  = blockIdx.x * 4 + wib;
  const int nwaves = gridDim.x * 4;

  float a0 = 0.f, a1 = 0.f, a2 = 0.f, a3 = 0.f;
  for (int e = gwave; e < E; e += nwaves) {
    float4 v = *reinterpret_cast<const float4*>(target + (size_t)e * EDIM + lane * 4);
    float ss = v.x * v.x + v.y * v.y + v.z * v.z + v.w * v.w;
#pragma unroll
    for (int off = 32; off >= 1; off >>= 1) ss += __shfl_xor(ss, off);
    float rn = (ss > 1e-35f) ? rsqrtf(ss) : 0.f;
    a0 += v.x * rn; a1 += v.y * rn; a2 += v.z * rn; a3 += v.w * rn;
  }
  red[wib][lane] = make_float4(a0, a1, a2, a3);
  __syncthreads();
  if (wib == 0) {
    float4 r0 = red[0][lane], r1 = red[1][lane], r2 = red[2][lane], r3 = red[3][lane];
    float4 o = make_float4(r0.x + r1.x + r2.x + r3.x,
                           r0.y + r1.y + r2.y + r3.y,
                           r0.z + r1.z + r2.z + r3.z,
                           r0.w + r1.w + r2.w + r3.w);
    *reinterpret_cast<float4*>(partial + (size_t)blockIdx.x * EDIM + lane * 4) = o;
  }
}

// Kernel A2: s[d] = sum_b partial[b][d]. One block, 256 threads, coalesced.
__global__ void __launch_bounds__(256) collapse_kernel(
    const float* __restrict__ partial, float* __restrict__ s) {
  const int t = threadIdx.x;
  float acc = 0.f;
#pragma unroll
  for (int b = 0; b < NPART; ++b) acc += partial[b * EDIM + t];
  s[t] = acc;
}

// Kernel B: out[n] = -(v_n . s) / ||v_n||.
// 8 lanes per row: lane = 8*r + c. Each load instruction fetches 8 rows x 128B
// contiguous (8 full cache lines). Reduction = 3 shuffle steps within 8 lanes.
__global__ void __launch_bounds__(256) dist_rowsum_kernel(
    const float* __restrict__ emb, const float* __restrict__ s,
    float* __restrict__ out, int N) {
  const int lane = threadIdx.x & 63;
  const int wib  = threadIdx.x >> 6;           // wave in block, 0..3
  const int r = lane >> 3;                     // row within wave's group of 8
  const int c = lane & 7;                      // d-chunk within row
  const int n = blockIdx.x * 32 + wib * 8 + r; // 32 rows per block

  // Preload this lane's 8 float4 slices of s (1 KB total, L1/L2 broadcast-hot).
  float4 sf[8];
#pragma unroll
  for (int j = 0; j < 8; ++j)
    sf[j] = *reinterpret_cast<const float4*>(s + j * 32 + c * 4);

  float dot = 0.f, ss = 0.f;
  if (n < N) {
    const float* row = emb + (size_t)n * EDIM;
#pragma unroll
    for (int j = 0; j < 8; ++j) {
      float4 v = *reinterpret_cast<const float4*>(row + j * 32 + c * 4);
      dot += v.x * sf[j].x + v.y * sf[j].y + v.z * sf[j].z + v.w * sf[j].w;
      ss  += v.x * v.x + v.y * v.y + v.z * v.z + v.w * v.w;
    }
  }
#pragma unroll
  for (int off = 1; off <= 4; off <<= 1) {
    dot += __shfl_xor(dot, off);
    ss  += __shfl_xor(ss, off);
  }
  if (c == 0 && n < N) {
    float d = sqrtf(ss);
    out[n] = (d > 0.f) ? (-dot / d) : 0.f;
  }
}

extern "C" void kernel_launch(void* const* d_in, const int* in_sizes, int n_in,
                              void* d_out, int out_size, void* d_ws, size_t ws_size,
                              hipStream_t stream) {
  // inputs: [0]=pred (unused), [1]=target [E,256], [2]=node_emb [N,256]
  const float* target = (const float*)d_in[1];
  const float* emb    = (const float*)d_in[2];
  float* out     = (float*)d_out;
  float* partial = (float*)d_ws;                  // NPART*EDIM floats
  float* s       = partial + NPART * EDIM;        // 256 floats

  const int E = in_sizes[1] / EDIM;
  const int N = in_sizes[2] / EDIM;

  dirsum_partial_kernel<<<NPART, 256, 0, stream>>>(target, partial, E);
  collapse_kernel<<<1, 256, 0, stream>>>(partial, s);
  dist_rowsum_kernel<<<(N + 31) / 32, 256, 0, stream>>>(emb, s, out, N);
}

// Round 4
// 19.204 us; speedup vs baseline: 2.1080x; 1.3216x over previous
//
#include <hip/hip_runtime.h>

#define EDIM 256   // embed dim, fixed by problem
#define NPART 32   // partial blocks for kernel A

// Kernel A: partial[b][d] = sum over this block's rows of target[e][d]/||t_e||.
// 32 blocks x 256 threads. 8 lanes per row (lane = r*8 + c), 8 rows per wave,
// so each thread issues 8 independent float4 loads per sweep. Row-norm reduce
// is 3 shuffle steps within the 8-lane group. Block collapse via LDS.
__global__ void __launch_bounds__(256) dirsum_partial_kernel(
    const float* __restrict__ target, float* __restrict__ partial, int E) {
  __shared__ float lds[32][EDIM];   // [wib*8+r][d]
  const int lane = threadIdx.x & 63;
  const int wib  = threadIdx.x >> 6;      // 0..3
  const int r    = lane >> 3;             // 0..7 row group
  const int c    = lane & 7;              // 0..7 d-chunk
  const int gwave = blockIdx.x * 4 + wib; // 0..127
  const int rows_per_sweep = NPART * 4 * 8;  // 1024

  float4 acc[8];
#pragma unroll
  for (int j = 0; j < 8; ++j) acc[j] = make_float4(0.f, 0.f, 0.f, 0.f);

  for (int base = 0; base < E; base += rows_per_sweep) {
    const int e = base + gwave * 8 + r;
    if (e < E) {
      const float* row = target + (size_t)e * EDIM;
      float4 v[8];
#pragma unroll
      for (int j = 0; j < 8; ++j)
        v[j] = *reinterpret_cast<const float4*>(row + j * 32 + c * 4);
      float ss = 0.f;
#pragma unroll
      for (int j = 0; j < 8; ++j)
        ss += v[j].x * v[j].x + v[j].y * v[j].y + v[j].z * v[j].z + v[j].w * v[j].w;
#pragma unroll
      for (int off = 1; off <= 4; off <<= 1) ss += __shfl_xor(ss, off);
      float rn = (ss > 1e-35f) ? rsqrtf(ss) : 0.f;
#pragma unroll
      for (int j = 0; j < 8; ++j) {
        acc[j].x += v[j].x * rn; acc[j].y += v[j].y * rn;
        acc[j].z += v[j].z * rn; acc[j].w += v[j].w * rn;
      }
    }
  }

  // lane (wib,r,c) holds acc[j] for d = j*32 + c*4 .. +3
#pragma unroll
  for (int j = 0; j < 8; ++j)
    *reinterpret_cast<float4*>(&lds[wib * 8 + r][j * 32 + c * 4]) = acc[j];
  __syncthreads();

  const int t = threadIdx.x;   // one d per thread
  float p = 0.f;
#pragma unroll
  for (int g = 0; g < 32; ++g) p += lds[g][t];
  partial[(size_t)blockIdx.x * EDIM + t] = p;
}

// Kernel B: out[n] = -(v_n . s) / ||v_n||,  s = sum of the 32 partials.
// Prologue: block collapses partials into LDS (L2-hot). Main: 8 lanes/row,
// 2 rows per thread (16 independent float4 loads in flight), 64 rows/block.
__global__ void __launch_bounds__(256) dist_rowsum_kernel(
    const float* __restrict__ emb, const float* __restrict__ partial,
    float* __restrict__ out, int N) {
  __shared__ float s_lds[EDIM];
  const int t = threadIdx.x;
  {
    float a = 0.f;
#pragma unroll
    for (int b = 0; b < NPART; ++b) a += partial[b * EDIM + t];
    s_lds[t] = a;
  }
  __syncthreads();

  const int lane = threadIdx.x & 63;
  const int wib  = threadIdx.x >> 6;       // 0..3
  const int r    = lane >> 3;              // 0..7
  const int c    = lane & 7;               // 0..7

  // This lane's 8 float4 slices of s from LDS (conflict-free / broadcast).
  float4 sf[8];
#pragma unroll
  for (int j = 0; j < 8; ++j)
    sf[j] = *reinterpret_cast<const float4*>(&s_lds[j * 32 + c * 4]);

  const int n0 = blockIdx.x * 64 + wib * 16 + r;   // rows n0 and n0+8
  const int n1 = n0 + 8;

  float4 v0[8], v1[8];
  const bool ok0 = (n0 < N), ok1 = (n1 < N);
  const float* row0 = emb + (size_t)n0 * EDIM;
  const float* row1 = emb + (size_t)n1 * EDIM;
  if (ok0) {
#pragma unroll
    for (int j = 0; j < 8; ++j)
      v0[j] = *reinterpret_cast<const float4*>(row0 + j * 32 + c * 4);
  }
  if (ok1) {
#pragma unroll
    for (int j = 0; j < 8; ++j)
      v1[j] = *reinterpret_cast<const float4*>(row1 + j * 32 + c * 4);
  }

  float dot0 = 0.f, ss0 = 0.f, dot1 = 0.f, ss1 = 0.f;
  if (ok0) {
#pragma unroll
    for (int j = 0; j < 8; ++j) {
      dot0 += v0[j].x * sf[j].x + v0[j].y * sf[j].y + v0[j].z * sf[j].z + v0[j].w * sf[j].w;
      ss0  += v0[j].x * v0[j].x + v0[j].y * v0[j].y + v0[j].z * v0[j].z + v0[j].w * v0[j].w;
    }
  }
  if (ok1) {
#pragma unroll
    for (int j = 0; j < 8; ++j) {
      dot1 += v1[j].x * sf[j].x + v1[j].y * sf[j].y + v1[j].z * sf[j].z + v1[j].w * sf[j].w;
      ss1  += v1[j].x * v1[j].x + v1[j].y * v1[j].y + v1[j].z * v1[j].z + v1[j].w * v1[j].w;
    }
  }
#pragma unroll
  for (int off = 1; off <= 4; off <<= 1) {
    dot0 += __shfl_xor(dot0, off);
    ss0  += __shfl_xor(ss0, off);
    dot1 += __shfl_xor(dot1, off);
    ss1  += __shfl_xor(ss1, off);
  }
  if (c == 0) {
    if (ok0) { float d = sqrtf(ss0); out[n0] = (d > 0.f) ? (-dot0 / d) : 0.f; }
    if (ok1) { float d = sqrtf(ss1); out[n1] = (d > 0.f) ? (-dot1 / d) : 0.f; }
  }
}

extern "C" void kernel_launch(void* const* d_in, const int* in_sizes, int n_in,
                              void* d_out, int out_size, void* d_ws, size_t ws_size,
                              hipStream_t stream) {
  // inputs: [0]=pred (unused), [1]=target [E,256], [2]=node_emb [N,256]
  const float* target = (const float*)d_in[1];
  const float* emb    = (const float*)d_in[2];
  float* out     = (float*)d_out;
  float* partial = (float*)d_ws;   // NPART * EDIM floats, fully rewritten each call

  const int E = in_sizes[1] / EDIM;
  const int N = in_sizes[2] / EDIM;

  dirsum_partial_kernel<<<NPART, 256, 0, stream>>>(target, partial, E);
  dist_rowsum_kernel<<<(N + 63) / 64, 256, 0, stream>>>(emb, partial, out, N);
}